// Round 4
// baseline (29588.177 us; speedup 1.0000x reference)
//
#include <hip/hip_runtime.h>
#include <stdint.h>

typedef _Float16 f16;
typedef _Float16 f16x8 __attribute__((ext_vector_type(8)));
typedef float f32x4 __attribute__((ext_vector_type(4)));

#define LN_EPS 1e-5f

// ---------------- chunk barrier ----------------
__device__ __forceinline__ void bar_sync(uint32_t* cnt, uint32_t* gen,
                                         uint32_t n, uint32_t target) {
  __syncthreads();  // drains each wave's vmem stores (compiler emits vmcnt(0))
  if (threadIdx.x == 0) {
    __builtin_amdgcn_fence(__ATOMIC_RELEASE, "agent");
    uint32_t t = __hip_atomic_fetch_add(cnt, 1u, __ATOMIC_ACQ_REL,
                                        __HIP_MEMORY_SCOPE_AGENT);
    if (t == n - 1u) {
      __hip_atomic_store(cnt, 0u, __ATOMIC_RELAXED, __HIP_MEMORY_SCOPE_AGENT);
      __hip_atomic_store(gen, target, __ATOMIC_RELEASE, __HIP_MEMORY_SCOPE_AGENT);
    } else {
      while (__hip_atomic_load(gen, __ATOMIC_RELAXED,
                               __HIP_MEMORY_SCOPE_AGENT) < target) {
        __builtin_amdgcn_s_sleep(1);
      }
    }
    __builtin_amdgcn_fence(__ATOMIC_ACQUIRE, "agent");
  }
  __syncthreads();
}

// ---------------- per-row GRU gate/LN update (one wave per row) ---------------
__device__ __forceinline__ void gru_row(
    int lane,
    const float* __restrict__ prow,   // rz pre-acts, col n = i*64+lane, 1024 cols
    const float* __restrict__ hu,     // recurrent h-part, 512 cols
    const f16*   __restrict__ xh16,   // x-part of h (f16) or null
    const float* __restrict__ xh32,   // x-part of h (f32) or null
    const float* __restrict__ grz, const float* __restrict__ brz,
    const float* __restrict__ gh,  const float* __restrict__ bh,
    float* __restrict__ hF,           // fp32 master row (LDS)
    f16*   __restrict__ hS,           // fp16 MFMA row (LDS)
    f16*   __restrict__ hall)         // optional global h_all row or null
{
  float v[16];
  float s1 = 0.f, s2 = 0.f;
#pragma unroll
  for (int i = 0; i < 16; ++i) v[i] = prow[i * 64 + lane];
#pragma unroll
  for (int i = 0; i < 16; ++i) { s1 += v[i]; s2 += v[i] * v[i]; }
#pragma unroll
  for (int off = 1; off < 64; off <<= 1) {
    s1 += __shfl_xor(s1, off); s2 += __shfl_xor(s2, off);
  }
  float m    = s1 * (1.f / 1024.f);
  float var  = s2 * (1.f / 1024.f) - m * m;
  float rstd = rsqrtf(var + LN_EPS);
  float rg[8], zg[8];
#pragma unroll
  for (int i = 0; i < 16; ++i) {
    int n = i * 64 + lane;
    float a = (v[i] - m) * rstd * grz[n] + brz[n];
    float s = 1.f / (1.f + __expf(-a));
    if (i < 8) rg[i] = s; else zg[i - 8] = s;
  }
  float ht[8];
  float u1 = 0.f, u2 = 0.f;
#pragma unroll
  for (int i = 0; i < 8; ++i) {
    int n = i * 64 + lane;
    float xv = xh16 ? (float)xh16[n] : xh32[n];
    float hv = xv + rg[i] * hu[n];
    ht[i] = hv; u1 += hv; u2 += hv * hv;
  }
#pragma unroll
  for (int off = 1; off < 64; off <<= 1) {
    u1 += __shfl_xor(u1, off); u2 += __shfl_xor(u2, off);
  }
  float m2    = u1 * (1.f / 512.f);
  float var2  = u2 * (1.f / 512.f) - m2 * m2;
  float rstd2 = rsqrtf(var2 + LN_EPS);
#pragma unroll
  for (int i = 0; i < 8; ++i) {
    int n = i * 64 + lane;
    float a  = (ht[i] - m2) * rstd2 * gh[n] + bh[n];
    float th = tanhf(a);
    float hp = hF[n];
    float hn = (1.f - zg[i]) * hp + zg[i] * th;
    hF[n] = hn;
    hS[n] = (f16)hn;
    if (hall) hall[n] = (f16)hn;
  }
}

// ---------------- merged 2-layer pipelined scan ----------------
// 4 chunks x 28 WGs = 112 WGs (1/CU, co-resident).  Per chunk (16 batch rows):
//   roles 0..11  (L0) : pre0 cols role*128,       K=512 (U0), phaseB: h0
//   roles 12..19 (RZ1): pre1 rz cols (r-12)*128,  K=1024 (W1rz + U1rz), phaseB: h0+h1
//   roles 20..23 (XH1): pre1 xh cols (r-20)*128,  K=512 (W1h),  phaseB: h0
//   roles 24..27 (HU1): pre1 hu cols (r-24)*128,  K=512 (U1h),  phaseB: h1
// ONE chunk barrier per step. pre0/pre1 are DOUBLE-BUFFERED by step parity:
// phase A(t+1) writes buffer (t+1)&1 while laggard WGs still read buffer t&1
// in phase B(t) — closes the WAR race that one-barrier-per-step creates.
__global__ __launch_bounds__(256, 1) void scan2_kernel(
    const f16* __restrict__ X0,   // [512][64][1536] x@[wrz0;wh0]+bias0
    const f16* __restrict__ U0,   // [1536][512]
    const f16* __restrict__ W1,   // [1536][512] = [wrz1; wh1]
    const f16* __restrict__ U1,   // [1536][512] = [urz1; uh1]
    const float* __restrict__ b_rz1, const float* __restrict__ b_h1,
    const float* __restrict__ g_rz0, const float* __restrict__ be_rz0,
    const float* __restrict__ g_h0,  const float* __restrict__ be_h0,
    const float* __restrict__ g_rz1, const float* __restrict__ be_rz1,
    const float* __restrict__ g_h1,  const float* __restrict__ be_h1,
    f16* __restrict__ h_all1,     // [512][64][512]
    float* __restrict__ pre0,     // [2][4][16][1536]  (parity-buffered)
    float* __restrict__ pre1,     // [2][4][16][2048]
    float* __restrict__ hidden,   // d_out + 16777216 : [2][64][512]
    uint32_t* __restrict__ bars)
{
  const int chunk = blockIdx.x / 28;
  const int role  = blockIdx.x % 28;
  const int rows0 = chunk * 16;
  const int tid   = threadIdx.x;
  const int wid   = tid >> 6;
  const int lane  = tid & 63;
  const int quad  = lane >> 4;
  const int l16   = lane & 15;

  int roleKind, colbase;
  if (role < 12)      { roleKind = 0; colbase = role * 128; }
  else if (role < 20) { roleKind = 1; colbase = (role - 12) * 128; }
  else if (role < 24) { roleKind = 2; colbase = (role - 20) * 128; }
  else                { roleKind = 3; colbase = (role - 24) * 128; }
  const int nw = colbase + wid * 32;

  __shared__ f16   h0s[16][520];
  __shared__ f16   h1s[16][520];
  __shared__ float h0f[16][512];
  __shared__ float h1f[16][512];
  for (int i = tid; i < 16 * 520; i += 256) { (&h0s[0][0])[i] = (f16)0.f; (&h1s[0][0])[i] = (f16)0.f; }
  for (int i = tid; i < 16 * 512; i += 256) { (&h0f[0][0])[i] = 0.f; (&h1f[0][0])[i] = 0.f; }

  // weight fragment preload (resident in VGPRs for all 513 steps)
  const f16* WA; const f16* WB;
  if      (roleKind == 0) { WA = U0 + (size_t)nw * 512;          WB = WA; }
  else if (roleKind == 1) { WA = W1 + (size_t)nw * 512;          WB = U1 + (size_t)nw * 512; }
  else if (roleKind == 2) { WA = W1 + (size_t)(1024 + nw) * 512; WB = WA; }
  else                    { WA = U1 + (size_t)(1024 + nw) * 512; WB = WA; }
  f16x8 wa[2][16], wb[2][16];
#pragma unroll
  for (int c = 0; c < 2; ++c)
#pragma unroll
    for (int kk = 0; kk < 16; ++kk) {
      wa[c][kk] = *(const f16x8*)(WA + (size_t)(c * 16 + l16) * 512 + kk * 32 + quad * 8);
      wb[c][kk] = *(const f16x8*)(WB + (size_t)(c * 16 + l16) * 512 + kk * 32 + quad * 8);
    }

  uint32_t* cnt = bars + (size_t)chunk * 128;
  uint32_t* gen = cnt + 64;

  for (int t = 0; t <= 512; ++t) {
    __syncthreads();  // phase B (t-1) LDS h-writes -> phase A (t) reads

    float* pre0c = pre0 + ((size_t)(t & 1) * 4 + chunk) * 16 * 1536;
    float* pre1c = pre1 + ((size_t)(t & 1) * 4 + chunk) * 16 * 2048;

    // ---------------- phase A ----------------
    f32x4 acc[2];
    if (roleKind == 0) {
      if (t < 512) {
        if (colbase < 1024) {
          const size_t xb = ((size_t)t * 64 + rows0 + quad * 4) * 1536 + nw + l16;
#pragma unroll
          for (int c = 0; c < 2; ++c)
#pragma unroll
            for (int rr = 0; rr < 4; ++rr)
              acc[c][rr] = (float)X0[xb + (size_t)rr * 1536 + c * 16];
        } else {
#pragma unroll
          for (int c = 0; c < 2; ++c) acc[c] = (f32x4){0.f, 0.f, 0.f, 0.f};
        }
#pragma unroll
        for (int kk = 0; kk < 16; ++kk) {
          f16x8 af = *(const f16x8*)&h0s[l16][kk * 32 + quad * 8];
          acc[0] = __builtin_amdgcn_mfma_f32_16x16x32_f16(af, wa[0][kk], acc[0], 0, 0, 0);
          acc[1] = __builtin_amdgcn_mfma_f32_16x16x32_f16(af, wa[1][kk], acc[1], 0, 0, 0);
        }
#pragma unroll
        for (int c = 0; c < 2; ++c)
#pragma unroll
          for (int rr = 0; rr < 4; ++rr)
            pre0c[(size_t)(quad * 4 + rr) * 1536 + nw + c * 16 + l16] = acc[c][rr];
      }
    } else if (roleKind == 1) {
#pragma unroll
      for (int c = 0; c < 2; ++c)
#pragma unroll
        for (int rr = 0; rr < 4; ++rr)
          acc[c][rr] = b_rz1[nw + c * 16 + l16];
#pragma unroll
      for (int kk = 0; kk < 16; ++kk) {
        f16x8 af = *(const f16x8*)&h0s[l16][kk * 32 + quad * 8];
        acc[0] = __builtin_amdgcn_mfma_f32_16x16x32_f16(af, wa[0][kk], acc[0], 0, 0, 0);
        acc[1] = __builtin_amdgcn_mfma_f32_16x16x32_f16(af, wa[1][kk], acc[1], 0, 0, 0);
      }
#pragma unroll
      for (int kk = 0; kk < 16; ++kk) {
        f16x8 af = *(const f16x8*)&h1s[l16][kk * 32 + quad * 8];
        acc[0] = __builtin_amdgcn_mfma_f32_16x16x32_f16(af, wb[0][kk], acc[0], 0, 0, 0);
        acc[1] = __builtin_amdgcn_mfma_f32_16x16x32_f16(af, wb[1][kk], acc[1], 0, 0, 0);
      }
#pragma unroll
      for (int c = 0; c < 2; ++c)
#pragma unroll
        for (int rr = 0; rr < 4; ++rr)
          pre1c[(size_t)(quad * 4 + rr) * 2048 + nw + c * 16 + l16] = acc[c][rr];
    } else if (roleKind == 2) {
#pragma unroll
      for (int c = 0; c < 2; ++c)
#pragma unroll
        for (int rr = 0; rr < 4; ++rr)
          acc[c][rr] = b_h1[nw + c * 16 + l16];
#pragma unroll
      for (int kk = 0; kk < 16; ++kk) {
        f16x8 af = *(const f16x8*)&h0s[l16][kk * 32 + quad * 8];
        acc[0] = __builtin_amdgcn_mfma_f32_16x16x32_f16(af, wa[0][kk], acc[0], 0, 0, 0);
        acc[1] = __builtin_amdgcn_mfma_f32_16x16x32_f16(af, wa[1][kk], acc[1], 0, 0, 0);
      }
#pragma unroll
      for (int c = 0; c < 2; ++c)
#pragma unroll
        for (int rr = 0; rr < 4; ++rr)
          pre1c[(size_t)(quad * 4 + rr) * 2048 + 1024 + nw + c * 16 + l16] = acc[c][rr];
    } else {
#pragma unroll
      for (int c = 0; c < 2; ++c) acc[c] = (f32x4){0.f, 0.f, 0.f, 0.f};
#pragma unroll
      for (int kk = 0; kk < 16; ++kk) {
        f16x8 af = *(const f16x8*)&h1s[l16][kk * 32 + quad * 8];
        acc[0] = __builtin_amdgcn_mfma_f32_16x16x32_f16(af, wa[0][kk], acc[0], 0, 0, 0);
        acc[1] = __builtin_amdgcn_mfma_f32_16x16x32_f16(af, wa[1][kk], acc[1], 0, 0, 0);
      }
#pragma unroll
      for (int c = 0; c < 2; ++c)
#pragma unroll
        for (int rr = 0; rr < 4; ++rr)
          pre1c[(size_t)(quad * 4 + rr) * 2048 + 1536 + nw + c * 16 + l16] = acc[c][rr];
    }

    bar_sync(cnt, gen, 28, (uint32_t)t + 1u);

    // ---------------- phase B (redundant per WG) ----------------
    // h0[t] for roles that feed MFMAs from h0s next step
    if (t < 512 && roleKind <= 2) {
#pragma unroll 1
      for (int j = 0; j < 4; ++j) {
        int r = wid * 4 + j;
        gru_row(lane,
                pre0c + (size_t)r * 1536,
                pre0c + (size_t)r * 1536 + 1024,
                X0 + ((size_t)t * 64 + rows0 + r) * 1536 + 1024, nullptr,
                g_rz0, be_rz0, g_h0, be_h0,
                h0f[r], h0s[r], nullptr);
      }
    }
    // h1[t-1] for roles that feed MFMAs from h1s next step
    if (t >= 1 && (roleKind == 1 || roleKind == 3)) {
      const bool wr = (role == 24);
#pragma unroll 1
      for (int j = 0; j < 4; ++j) {
        int r = wid * 4 + j;
        gru_row(lane,
                pre1c + (size_t)r * 2048,
                pre1c + (size_t)r * 2048 + 1536,
                nullptr, pre1c + (size_t)r * 2048 + 1024,
                g_rz1, be_rz1, g_h1, be_h1,
                h1f[r], h1s[r],
                wr ? (h_all1 + ((size_t)(t - 1) * 64 + rows0 + r) * 512) : nullptr);
      }
    }
  }

  // final hidden states
  __syncthreads();
  if (role == 0)
    for (int i = tid; i < 16 * 512; i += 256)
      hidden[(size_t)(rows0 + (i >> 9)) * 512 + (i & 511)] = h0f[i >> 9][i & 511];
  if (role == 24)
    for (int i = tid; i < 16 * 512; i += 256)
      hidden[32768 + (size_t)(rows0 + (i >> 9)) * 512 + (i & 511)] = h1f[i >> 9][i & 511];
}

// ---------------- generic K=512 fp16 GEMM: C = A @ W^T + bias ----------------
__global__ void gemm_k512(const f16* __restrict__ A, const f16* __restrict__ W,
                          const float* __restrict__ bias, void* __restrict__ out,
                          int N, int mode)
{
  __shared__ f16 As[128][56];
  __shared__ f16 Bs[128][56];
  const int tid = threadIdx.x;
  const int wid = tid >> 6, lane = tid & 63, quad = lane >> 4, l16 = lane & 15;
  const int wm = wid & 1, wn = wid >> 1;
  const int rb = blockIdx.y * 128, cb = blockIdx.x * 128;
  f32x4 acc[4][4];
#pragma unroll
  for (int i = 0; i < 4; ++i)
#pragma unroll
    for (int j = 0; j < 4; ++j) acc[i][j] = (f32x4){0.f, 0.f, 0.f, 0.f};
  const int srow = tid >> 1;
  const int skh  = (tid & 1) * 16;
  for (int kk = 0; kk < 16; ++kk) {
    __syncthreads();
    {
      const f16* a = A + (size_t)(rb + srow) * 512 + kk * 32 + skh;
      *(f16x8*)&As[srow][skh]     = *(const f16x8*)(a);
      *(f16x8*)&As[srow][skh + 8] = *(const f16x8*)(a + 8);
      const f16* b = W + (size_t)(cb + srow) * 512 + kk * 32 + skh;
      *(f16x8*)&Bs[srow][skh]     = *(const f16x8*)(b);
      *(f16x8*)&Bs[srow][skh + 8] = *(const f16x8*)(b + 8);
    }
    __syncthreads();
    f16x8 af[4], bf[4];
#pragma unroll
    for (int mt = 0; mt < 4; ++mt) af[mt] = *(const f16x8*)&As[wm * 64 + mt * 16 + l16][quad * 8];
#pragma unroll
    for (int nt = 0; nt < 4; ++nt) bf[nt] = *(const f16x8*)&Bs[wn * 64 + nt * 16 + l16][quad * 8];
#pragma unroll
    for (int mt = 0; mt < 4; ++mt)
#pragma unroll
      for (int nt = 0; nt < 4; ++nt)
        acc[mt][nt] = __builtin_amdgcn_mfma_f32_16x16x32_f16(af[mt], bf[nt], acc[mt][nt], 0, 0, 0);
  }
#pragma unroll
  for (int mt = 0; mt < 4; ++mt) {
#pragma unroll
    for (int nt = 0; nt < 4; ++nt) {
#pragma unroll
      for (int rr = 0; rr < 4; ++rr) {
        int grow = rb + wm * 64 + mt * 16 + quad * 4 + rr;
        int gcol = cb + wn * 64 + nt * 16 + l16;
        float vv = acc[mt][nt][rr] + bias[gcol];
        if (mode == 0) {
          ((f16*)out)[(size_t)grow * N + gcol] = (f16)vv;
        } else {
          int b = grow & 63, tt = grow >> 6;
          ((float*)out)[((size_t)b * 512 + tt) * 512 + gcol] = vv;
        }
      }
    }
  }
}

// ---------------- prep ----------------
__global__ void prep_kernel(
    const float* __restrict__ x, const float* __restrict__ fc_w,
    const float* __restrict__ w_rz0, const float* __restrict__ b_rz0,
    const float* __restrict__ u_rz0, const float* __restrict__ w_h0,
    const float* __restrict__ b_h0,  const float* __restrict__ u_h0,
    const float* __restrict__ w_rz1, const float* __restrict__ u_rz1,
    const float* __restrict__ w_h1,  const float* __restrict__ u_h1,
    f16* x16, f16* wcat0, f16* ucat0, f16* wcat1, f16* ucat1, f16* fcw16,
    float* bias0, uint32_t* bars)
{
  const int stride = gridDim.x * blockDim.x;
  const int gid = blockIdx.x * blockDim.x + threadIdx.x;
  for (int i = gid; i < 16777216; i += stride) {
    int k = i & 511, b = (i >> 9) & 63, t = i >> 15;
    x16[i] = (f16)x[(((size_t)b << 9) + t) * 512 + k];
  }
  for (int i = gid; i < 786432; i += stride) {
    int n = i >> 9, k = i & 511;
    float a0 = (n < 1024) ? w_rz0[(size_t)n * 512 + k] : w_h0[(size_t)(n - 1024) * 512 + k];
    float c0 = (n < 1024) ? u_rz0[(size_t)n * 512 + k] : u_h0[(size_t)(n - 1024) * 512 + k];
    float a1 = (n < 1024) ? w_rz1[(size_t)n * 512 + k] : w_h1[(size_t)(n - 1024) * 512 + k];
    float c1 = (n < 1024) ? u_rz1[(size_t)n * 512 + k] : u_h1[(size_t)(n - 1024) * 512 + k];
    wcat0[i] = (f16)a0; ucat0[i] = (f16)c0; wcat1[i] = (f16)a1; ucat1[i] = (f16)c1;
  }
  for (int i = gid; i < 262144; i += stride) fcw16[i] = (f16)fc_w[i];
  for (int i = gid; i < 1536; i += stride)
    bias0[i] = (i < 1024) ? b_rz0[i] : b_h0[i - 1024];
  for (int i = gid; i < 1024; i += stride) bars[i] = 0u;
}

extern "C" void kernel_launch(void* const* d_in, const int* in_sizes, int n_in,
                              void* d_out, int out_size, void* d_ws, size_t ws_size,
                              hipStream_t stream)
{
  const float* x      = (const float*)d_in[0];
  const float* fc_w   = (const float*)d_in[1];
  const float* fc_b   = (const float*)d_in[2];
  const float* l0_w_rz = (const float*)d_in[3];
  const float* l0_b_rz = (const float*)d_in[4];
  const float* l0_u_rz = (const float*)d_in[5];
  const float* l0_w_h  = (const float*)d_in[6];
  const float* l0_b_h  = (const float*)d_in[7];
  const float* l0_u_h  = (const float*)d_in[8];
  const float* l0_g_rz = (const float*)d_in[9];
  const float* l0_be_rz= (const float*)d_in[10];
  const float* l0_g_h  = (const float*)d_in[11];
  const float* l0_be_h = (const float*)d_in[12];
  const float* l1_w_rz = (const float*)d_in[13];
  const float* l1_b_rz = (const float*)d_in[14];
  const float* l1_u_rz = (const float*)d_in[15];
  const float* l1_w_h  = (const float*)d_in[16];
  const float* l1_b_h  = (const float*)d_in[17];
  const float* l1_u_h  = (const float*)d_in[18];
  const float* l1_g_rz = (const float*)d_in[19];
  const float* l1_be_rz= (const float*)d_in[20];
  const float* l1_g_h  = (const float*)d_in[21];
  const float* l1_be_h = (const float*)d_in[22];

  char* ws = (char*)d_ws;
  size_t off = 0;
  auto alloc = [&](size_t bytes) {
    size_t o = off; off += (bytes + 255) & ~(size_t)255; return o;
  };
  f16*   X0     = (f16*)  (ws + alloc((size_t)512 * 64 * 1536 * 2));
  f16*   x16    = (f16*)  (ws + alloc((size_t)512 * 64 * 512 * 2));
  f16*   h_all1 = (f16*)  (ws + alloc((size_t)512 * 64 * 512 * 2));
  f16*   wcat0  = (f16*)  (ws + alloc((size_t)1536 * 512 * 2));
  f16*   ucat0  = (f16*)  (ws + alloc((size_t)1536 * 512 * 2));
  f16*   wcat1  = (f16*)  (ws + alloc((size_t)1536 * 512 * 2));
  f16*   ucat1  = (f16*)  (ws + alloc((size_t)1536 * 512 * 2));
  f16*   fcw16  = (f16*)  (ws + alloc((size_t)512 * 512 * 2));
  float* bias0  = (float*)(ws + alloc((size_t)1536 * 4));
  float* pre0   = (float*)(ws + alloc((size_t)2 * 4 * 16 * 1536 * 4));  // parity dbuf
  float* pre1   = (float*)(ws + alloc((size_t)2 * 4 * 16 * 2048 * 4));  // parity dbuf
  uint32_t* bars= (uint32_t*)(ws + alloc((size_t)1024 * 4));

  prep_kernel<<<dim3(2048), dim3(256), 0, stream>>>(
      x, fc_w, l0_w_rz, l0_b_rz, l0_u_rz, l0_w_h, l0_b_h, l0_u_h,
      l1_w_rz, l1_u_rz, l1_w_h, l1_u_h,
      x16, wcat0, ucat0, wcat1, ucat1, fcw16, bias0, bars);

  // X0 = x @ [w_rz0; w_h0]^T + bias0
  gemm_k512<<<dim3(12, 256), dim3(256), 0, stream>>>(x16, wcat0, bias0, X0, 1536, 0);

  // merged pipelined 2-layer scan
  scan2_kernel<<<dim3(112), dim3(256), 0, stream>>>(
      X0, ucat0, wcat1, ucat1, l1_b_rz, l1_b_h,
      l0_g_rz, l0_be_rz, l0_g_h, l0_be_h,
      l1_g_rz, l1_be_rz, l1_g_h, l1_be_h,
      h_all1, pre0, pre1, (float*)d_out + 16777216, bars);

  // logits = h_all1 @ fc_w^T + fc_b
  gemm_k512<<<dim3(4, 256), dim3(256), 0, stream>>>(h_all1, fcw16, fc_b, d_out, 512, 1);
}